// Round 9
// baseline (537.892 us; speedup 1.0000x reference)
//
#include <hip/hip_runtime.h>

#define N_NODES 100000
#define N_EDGES 1600000
#define N_GRAPHS 2048
#define DIM 128

// bucket CSR build params
#define NBUK 196      // ceil(100000/512)
#define BUKSH 9       // bucket = dst >> 9 (512 nodes per bucket)
#define NCH 256       // edge chunks (blocks) in passes A/C
#define EPB 6250      // edges per chunk = N_EDGES / NCH
#define NMAT (NBUK * NCH)  // 50176

typedef short short8v __attribute__((ext_vector_type(8)));
typedef float float4v __attribute__((ext_vector_type(4)));

__device__ __forceinline__ unsigned short f2bf(float f) {
  union { float f; unsigned u; } x; x.f = f;
  unsigned r = x.u + 0x7fffu + ((x.u >> 16) & 1u);
  return (unsigned short)(r >> 16);
}
__device__ __forceinline__ float bfhi2f(unsigned bits) {  // bits already in high half
  union { unsigned u; float f; } x; x.u = bits; return x.f;
}
__device__ __forceinline__ void accum8(float* p, uint4 v) {
  p[0] += bfhi2f(v.x << 16); p[1] += bfhi2f(v.x & 0xffff0000u);
  p[2] += bfhi2f(v.y << 16); p[3] += bfhi2f(v.y & 0xffff0000u);
  p[4] += bfhi2f(v.z << 16); p[5] += bfhi2f(v.z & 0xffff0000u);
  p[6] += bfhi2f(v.w << 16); p[7] += bfhi2f(v.w & 0xffff0000u);
}
// signed-byte extract -> float (v_bfe_i32 + v_cvt_f32_i32)
__device__ __forceinline__ float sb(unsigned w, int j) {
  return (float)(int)(signed char)((w >> (8 * j)) & 0xffu);
}
// accumulate 8 int8 (one uint2) scaled by s
__device__ __forceinline__ void accq(float* p, uint2 q, float s) {
  p[0] += sb(q.x, 0) * s; p[1] += sb(q.x, 1) * s;
  p[2] += sb(q.x, 2) * s; p[3] += sb(q.x, 3) * s;
  p[4] += sb(q.y, 0) * s; p[5] += sb(q.y, 1) * s;
  p[6] += sb(q.y, 2) * s; p[7] += sb(q.y, 3) * s;
}

// ---------------- bucket CSR build (write-combining by construction; R6 lesson) ----
__global__ __launch_bounds__(256) void k_bcount(const int* __restrict__ dst, int* __restrict__ cntmat) {
  __shared__ int cnt[NBUK];
  int b = blockIdx.x, t = threadIdx.x;
  if (t < NBUK) cnt[t] = 0;
  __syncthreads();
  int e0 = b * EPB;
  for (int j = t; j < EPB; j += 256) atomicAdd(&cnt[dst[e0 + j] >> BUKSH], 1);
  __syncthreads();
  if (t < NBUK) cntmat[t * NCH + b] = cnt[t];
}

__global__ __launch_bounds__(256) void k_scan1g(const int* __restrict__ in, int n,
                                                int* __restrict__ tmp, int* __restrict__ bsum) {
  __shared__ int sh[256];
  int b = blockIdx.x, t = threadIdx.x;
  int base = b * 1024 + t * 4;
  int v[4], s = 0;
#pragma unroll
  for (int i = 0; i < 4; i++) { v[i] = (base + i < n) ? in[base + i] : 0; s += v[i]; }
  sh[t] = s;
  __syncthreads();
  for (int off = 1; off < 256; off <<= 1) {
    int x = (t >= off) ? sh[t - off] : 0;
    __syncthreads();
    sh[t] += x;
    __syncthreads();
  }
  int run = sh[t] - s;
#pragma unroll
  for (int i = 0; i < 4; i++) { run += v[i]; if (base + i < n) tmp[base + i] = run; }
  if (t == 255) bsum[b] = sh[255];
}

__global__ void k_scan2g(int* __restrict__ bsum, int nb) {
  __shared__ int sh[128];
  int t = threadIdx.x;
  int v = (t < nb) ? bsum[t] : 0;
  sh[t] = v;
  __syncthreads();
  for (int off = 1; off < 128; off <<= 1) {
    int x = (t >= off) ? sh[t - off] : 0;
    __syncthreads();
    sh[t] += x;
    __syncthreads();
  }
  if (t < nb) bsum[t] = sh[t] - v;  // exclusive
}

__global__ __launch_bounds__(256) void k_exc(const int* __restrict__ tmp, const int* __restrict__ bsum,
                                             const int* __restrict__ in, int n, int* __restrict__ outExc) {
  int i = blockIdx.x * 256 + threadIdx.x;
  if (i < n) outExc[i] = tmp[i] + bsum[i >> 10] - in[i];
}

__global__ __launch_bounds__(256) void k_bscatter(const int* __restrict__ src, const int* __restrict__ dst,
                                                  const int* __restrict__ base, int2* __restrict__ epk) {
  __shared__ int cur[NBUK];
  int b = blockIdx.x, t = threadIdx.x;
  if (t < NBUK) cur[t] = base[t * NCH + b];
  __syncthreads();
  int e0 = b * EPB;
  for (int j = t; j < EPB; j += 256) {
    int s = src[e0 + j], d = dst[e0 + j];
    int pos = atomicAdd(&cur[d >> BUKSH], 1);
    epk[pos] = make_int2(s, d);
  }
}

__global__ __launch_bounds__(256) void k_bfinish(const int2* __restrict__ epk, const int* __restrict__ base,
                                                 int* __restrict__ rowptr, int* __restrict__ col) {
  __shared__ int a[512];
  __shared__ int sh[256];
  int k = blockIdx.x, t = threadIdx.x;
  int bstart = base[k * NCH];
  int bend = (k + 1 < NBUK) ? base[(k + 1) * NCH] : N_EDGES;
  a[t] = 0; a[t + 256] = 0;
  __syncthreads();
  for (int i = bstart + t; i < bend; i += 256) atomicAdd(&a[epk[i].y - (k << BUKSH)], 1);
  __syncthreads();
  int c0 = a[2 * t], c1 = a[2 * t + 1];
  int s = c0 + c1;
  sh[t] = s;
  __syncthreads();
  for (int off = 1; off < 256; off <<= 1) {
    int x = (t >= off) ? sh[t - off] : 0;
    __syncthreads();
    sh[t] += x;
    __syncthreads();
  }
  int excl = sh[t] - s;
  int st0 = bstart + excl;
  int st1 = st0 + c0;
  int g0 = (k << BUKSH) + 2 * t, g1 = g0 + 1;
  if (g0 < N_NODES) rowptr[g0] = st0;
  if (g1 < N_NODES) rowptr[g1] = st1;
  if (k == NBUK - 1 && t == 0) rowptr[N_NODES] = N_EDGES;
  __syncthreads();
  a[2 * t] = st0; a[2 * t + 1] = st1;  // convert to cursors
  __syncthreads();
  for (int i = bstart + t; i < bend; i += 256) {
    int2 e = epk[i];
    int pos = atomicAdd(&a[e.y - (k << BUKSH)], 1);
    col[pos] = e.x;
  }
}

// ---------------- graph boundary pointers (batch is sorted) ----------------
__global__ __launch_bounds__(256) void k_gptr(const int* __restrict__ batch, int* __restrict__ gptr) {
  int i = blockIdx.x * 256 + threadIdx.x;
  if (i >= N_NODES) return;
  int b = batch[i];
  int a = (i == 0) ? -1 : batch[i - 1];
  for (int g = a + 1; g <= b; g++) gptr[g] = i;
  if (i == N_NODES - 1) {
    for (int g = b + 1; g <= N_GRAPHS; g++) gptr[g] = N_NODES;
  }
}

// ---------------- dtype converts ----------------
__global__ __launch_bounds__(256) void k_cvtx(const float* __restrict__ x, unsigned short* __restrict__ h) {
  int i = blockIdx.x * 256 + threadIdx.x;  // over N*DIM/4
  if (i < N_NODES * DIM / 4) {
    float4 v = ((const float4*)x)[i];
    unsigned lo = (unsigned)f2bf(v.x) | ((unsigned)f2bf(v.y) << 16);
    unsigned hi = (unsigned)f2bf(v.z) | ((unsigned)f2bf(v.w) << 16);
    ((uint2*)h)[i] = make_uint2(lo, hi);
  }
}

// layer-0 int8 table + per-row scales from x. One wave per row; bytes staged
// through LDS so the global write is 8 lanes x 16B coalesced.
__global__ __launch_bounds__(256) void k_cvtq(const float* __restrict__ x,
                                              unsigned char* __restrict__ hq, float* __restrict__ sc) {
  __shared__ char qb[4][128];
  int wave = threadIdx.x >> 6, lane = threadIdx.x & 63;
  int r = blockIdx.x * 4 + wave;
  float a = x[(size_t)r * DIM + lane];
  float b = x[(size_t)r * DIM + 64 + lane];
  float m = fmaxf(fabsf(a), fabsf(b));
#pragma unroll
  for (int off = 1; off <= 32; off <<= 1) m = fmaxf(m, __shfl_xor(m, off, 64));
  float inv = m > 0.f ? 127.f / m : 0.f;
  if (lane == 0) sc[r] = m * (1.f / 127.f);
  qb[wave][lane] = (char)(int)rintf(a * inv);
  qb[wave][64 + lane] = (char)(int)rintf(b * inv);
  // single-wave LDS: DS ops in-order, no barrier needed
  if (lane < 8) {
    uint4 v = *(const uint4*)&qb[wave][lane * 16];
    *(uint4*)(hq + (size_t)r * DIM + lane * 16) = v;
  }
}

// Weights -> bf16 MFMA B-fragment order.
__global__ __launch_bounds__(256) void k_cvtw(const float* w0, const float* w1, const float* w2, const float* w3,
                                              const float* w4, const float* w5, const float* w6, const float* w7,
                                              unsigned short* __restrict__ wbF) {
  int i = blockIdx.x * 256 + threadIdx.x;
  if (i < 4 * 8 * 8 * 64 * 8) {
    int j = i & 7, l = (i >> 3) & 63, c = (i >> 9) & 7, kc = (i >> 12) & 7, layer = i >> 15;
    int m = layer * 2 + (kc >> 2);
    const float* w;
    switch (m) {
      case 0: w = w0; break; case 1: w = w1; break; case 2: w = w2; break; case 3: w = w3; break;
      case 4: w = w4; break; case 5: w = w5; break; case 6: w = w6; break; default: w = w7; break;
    }
    int kin = (kc & 3) * 32 + ((l >> 4) * 8) + j;
    int n = c * 16 + (l & 15);
    wbF[i] = f2bf(w[kin * 128 + n]);
  }
}

// ---------------- fused layer ----------------
// R9: gather payload int8 + per-row scale (row = 128B, half of bf16). R1-R8 proved
// the gather path saturates at ~2.9 TB/s with FETCH pinned at the compulsory floor
// (8-XCD L2 replication of random rows) -> bytes/row is the only remaining lever.
// Quant error <= rowmax/254 (~0.4% of rowmax) on the AGG TERM ONLY -> same order as
// the bf16 rounding already in the pipeline. Root term / MFMA / pool stay bf16-exact.
// Epilogue fuses next layer's quant: per-row max via shfl within 16-lane group,
// bytes staged through As (free after phase 2b; single wave -> in-order DS).
#define QLD(c) (*(const uint2*)(hq + (size_t)(c) * DIM + li * 8))
__global__ __launch_bounds__(64, 6) void k_fused(const int* __restrict__ rowptr,
                                                 const int* __restrict__ col,
                                                 const unsigned short* __restrict__ hIn,
                                                 const unsigned char* __restrict__ hq,
                                                 const float* __restrict__ sc,
                                                 const unsigned short* __restrict__ wbF,
                                                 const float* __restrict__ bias,
                                                 unsigned short* __restrict__ hOut,
                                                 unsigned char* __restrict__ hqOut,
                                                 float* __restrict__ scOut) {
  __shared__ uint4 As[256];  // 4 KB: 16 rows x 16 chunks; reused as byte buf in epilogue
  const int lane = threadIdx.x & 63;
  const int wrow0 = blockIdx.x * 16;   // grid exact: all 16 rows valid
  const int sub = lane >> 4, li = lane & 15;

  // ---- Phase 1: pair-interleaved int8 gather of 16 rows ----
  for (int ri = 0; ri < 16; ri += 2) {
    int nodeA = wrow0 + ri;
    float pA[8], pB[8];
#pragma unroll
    for (int j = 0; j < 8; j++) { pA[j] = 0.f; pB[j] = 0.f; }
    int eA = rowptr[nodeA], aS1 = rowptr[nodeA + 1];
    int eB = aS1, bS1 = rowptr[nodeA + 2];

    while (eA + 8 <= aS1 && eB + 8 <= bS1) {
      int cA0 = col[eA + sub], cA1 = col[eA + 4 + sub];
      int cB0 = col[eB + sub], cB1 = col[eB + 4 + sub];
      float sA0 = sc[cA0], sA1 = sc[cA1], sB0 = sc[cB0], sB1 = sc[cB1];
      uint2 vA0 = QLD(cA0), vA1 = QLD(cA1);
      uint2 vB0 = QLD(cB0), vB1 = QLD(cB1);
      accq(pA, vA0, sA0); accq(pA, vA1, sA1);
      accq(pB, vB0, sB0); accq(pB, vB1, sB1);
      eA += 8; eB += 8;
    }
    // drain A (chunk order: x16 / x8 / x4 / rem)
    for (; eA + 16 <= aS1; eA += 16) {
      int c0 = col[eA + sub], c1 = col[eA + 4 + sub], c2 = col[eA + 8 + sub], c3 = col[eA + 12 + sub];
      float s0 = sc[c0], s1 = sc[c1], s2 = sc[c2], s3 = sc[c3];
      uint2 v0 = QLD(c0), v1 = QLD(c1), v2 = QLD(c2), v3 = QLD(c3);
      accq(pA, v0, s0); accq(pA, v1, s1); accq(pA, v2, s2); accq(pA, v3, s3);
    }
    if (eA + 8 <= aS1) {
      int c0 = col[eA + sub], c1 = col[eA + 4 + sub];
      float s0 = sc[c0], s1 = sc[c1];
      uint2 v0 = QLD(c0), v1 = QLD(c1);
      accq(pA, v0, s0); accq(pA, v1, s1);
      eA += 8;
    }
    if (eA + 4 <= aS1) {
      int c0 = col[eA + sub];
      float s0 = sc[c0];
      uint2 v0 = QLD(c0);
      accq(pA, v0, s0);
      eA += 4;
    }
    if (eA + sub < aS1) {
      int c0 = col[eA + sub];
      float s0 = sc[c0];
      uint2 v0 = QLD(c0);
      accq(pA, v0, s0);
    }
    // drain B
    for (; eB + 16 <= bS1; eB += 16) {
      int c0 = col[eB + sub], c1 = col[eB + 4 + sub], c2 = col[eB + 8 + sub], c3 = col[eB + 12 + sub];
      float s0 = sc[c0], s1 = sc[c1], s2 = sc[c2], s3 = sc[c3];
      uint2 v0 = QLD(c0), v1 = QLD(c1), v2 = QLD(c2), v3 = QLD(c3);
      accq(pB, v0, s0); accq(pB, v1, s1); accq(pB, v2, s2); accq(pB, v3, s3);
    }
    if (eB + 8 <= bS1) {
      int c0 = col[eB + sub], c1 = col[eB + 4 + sub];
      float s0 = sc[c0], s1 = sc[c1];
      uint2 v0 = QLD(c0), v1 = QLD(c1);
      accq(pB, v0, s0); accq(pB, v1, s1);
      eB += 8;
    }
    if (eB + 4 <= bS1) {
      int c0 = col[eB + sub];
      float s0 = sc[c0];
      uint2 v0 = QLD(c0);
      accq(pB, v0, s0);
      eB += 4;
    }
    if (eB + sub < bS1) {
      int c0 = col[eB + sub];
      float s0 = sc[c0];
      uint2 v0 = QLD(c0);
      accq(pB, v0, s0);
    }

#pragma unroll
    for (int j = 0; j < 8; j++) {
      pA[j] += __shfl_xor(pA[j], 16, 64);
      pA[j] += __shfl_xor(pA[j], 32, 64);
      pB[j] += __shfl_xor(pB[j], 16, 64);
      pB[j] += __shfl_xor(pB[j], 32, 64);
    }
    if (sub == 0) {
      uint4 oA, oB;
      oA.x = (unsigned)f2bf(pA[0]) | ((unsigned)f2bf(pA[1]) << 16);
      oA.y = (unsigned)f2bf(pA[2]) | ((unsigned)f2bf(pA[3]) << 16);
      oA.z = (unsigned)f2bf(pA[4]) | ((unsigned)f2bf(pA[5]) << 16);
      oA.w = (unsigned)f2bf(pA[6]) | ((unsigned)f2bf(pA[7]) << 16);
      oB.x = (unsigned)f2bf(pB[0]) | ((unsigned)f2bf(pB[1]) << 16);
      oB.y = (unsigned)f2bf(pB[2]) | ((unsigned)f2bf(pB[3]) << 16);
      oB.z = (unsigned)f2bf(pB[4]) | ((unsigned)f2bf(pB[5]) << 16);
      oB.w = (unsigned)f2bf(pB[6]) | ((unsigned)f2bf(pB[7]) << 16);
      As[li * 16 + (ri ^ li)] = oA;
      As[li * 16 + ((ri + 1) ^ li)] = oB;
    }
  }

  float4v acc[8];
#pragma unroll
  for (int c2 = 0; c2 < 8; c2++)
#pragma unroll
    for (int i = 0; i < 4; i++) acc[c2][i] = 0.f;

  // ---- Phase 2a: agg @ Wrel (wbF kc 0..3) ----
#pragma unroll
  for (int kc = 0; kc < 4; kc++) {
    int c = kc * 4 + sub;
    short8v afr = *(const short8v*)&As[c * 16 + (li ^ c)];
#pragma unroll
    for (int c2 = 0; c2 < 8; c2++) {
      short8v bfr = *(const short8v*)(wbF + (size_t)((kc * 8 + c2) * 64 + lane) * 8);
      acc[c2] = __builtin_amdgcn_mfma_f32_16x16x32_bf16(afr, bfr, acc[c2], 0, 0, 0);
    }
  }

  // ---- restage own 16 h rows (bf16-exact root term) ----
#pragma unroll
  for (int j = 0; j < 4; j++) {
    int idx = j * 64 + lane;
    int r = idx >> 4, c = idx & 15;
    uint4 v = *(const uint4*)(hIn + (size_t)(wrow0 + r) * DIM + c * 8);
    As[c * 16 + (r ^ c)] = v;
  }

  // ---- Phase 2b: h @ Wroot (wbF kc 4..7) ----
#pragma unroll
  for (int kc = 0; kc < 4; kc++) {
    int c = kc * 4 + sub;
    short8v afr = *(const short8v*)&As[c * 16 + (li ^ c)];
#pragma unroll
    for (int c2 = 0; c2 < 8; c2++) {
      short8v bfr = *(const short8v*)(wbF + (size_t)(((4 + kc) * 8 + c2) * 64 + lane) * 8);
      acc[c2] = __builtin_amdgcn_mfma_f32_16x16x32_bf16(afr, bfr, acc[c2], 0, 0, 0);
    }
  }

  // ---- epilogue: bf16 out + fused int8 quant for next layer ----
  // D layout: col = c2*16+li, row = rbase + i (rbase = wrow0 + sub*4)
  int rbase = wrow0 + sub * 4;
  float bvv[8];
  float m0 = 0.f, m1 = 0.f, m2 = 0.f, m3 = 0.f;
#pragma unroll
  for (int c2 = 0; c2 < 8; c2++) {
    int colidx = c2 * 16 + li;
    bvv[c2] = bias[colidx];
#pragma unroll
    for (int i = 0; i < 4; i++) {
      float v = acc[c2][i] + bvv[c2];
      v = v > 0.f ? v : 0.f;
      hOut[(rbase + i) * DIM + colidx] = f2bf(v);
      if (i == 0) m0 = fmaxf(m0, v);
      else if (i == 1) m1 = fmaxf(m1, v);
      else if (i == 2) m2 = fmaxf(m2, v);
      else m3 = fmaxf(m3, v);
    }
  }
  // per-row max across the 16-lane li group (sub unchanged by masks <=8)
#pragma unroll
  for (int mask = 1; mask <= 8; mask <<= 1) {
    m0 = fmaxf(m0, __shfl_xor(m0, mask, 64));
    m1 = fmaxf(m1, __shfl_xor(m1, mask, 64));
    m2 = fmaxf(m2, __shfl_xor(m2, mask, 64));
    m3 = fmaxf(m3, __shfl_xor(m3, mask, 64));
  }
  float i0 = m0 > 0.f ? 127.f / m0 : 0.f;
  float i1 = m1 > 0.f ? 127.f / m1 : 0.f;
  float i2 = m2 > 0.f ? 127.f / m2 : 0.f;
  float i3 = m3 > 0.f ? 127.f / m3 : 0.f;
  if (li == 0) {
    scOut[rbase + 0] = m0 * (1.f / 127.f);
    scOut[rbase + 1] = m1 * (1.f / 127.f);
    scOut[rbase + 2] = m2 * (1.f / 127.f);
    scOut[rbase + 3] = m3 * (1.f / 127.f);
  }
  // quantize into As-as-bytes (As free after phase 2b; single wave -> in-order DS)
  char* qb = (char*)As;
#pragma unroll
  for (int c2 = 0; c2 < 8; c2++) {
#pragma unroll
    for (int i = 0; i < 4; i++) {
      float v = acc[c2][i] + bvv[c2];
      v = v > 0.f ? v : 0.f;
      float iv = (i == 0) ? i0 : (i == 1) ? i1 : (i == 2) ? i2 : i3;
      qb[(sub * 4 + i) * 128 + c2 * 16 + li] = (char)(int)rintf(v * iv);
    }
  }
  // pack out: 2048 B = 128 x 16B chunks; 2 chunks per lane, coalesced
  {
    int k0 = lane, k1 = lane + 64;
    uint4 w0 = *(const uint4*)(qb + k0 * 16);
    uint4 w1 = *(const uint4*)(qb + k1 * 16);
    *(uint4*)(hqOut + (size_t)(wrow0 + (k0 >> 3)) * DIM + (k0 & 7) * 16) = w0;
    *(uint4*)(hqOut + (size_t)(wrow0 + (k1 >> 3)) * DIM + (k1 & 7) * 16) = w1;
  }
}

// ---------------- pooling ----------------
__global__ __launch_bounds__(256) void k_pool(const unsigned short* __restrict__ h,
                                              const int* __restrict__ gptr,
                                              float* __restrict__ pooledMean) {
  int g = blockIdx.x * 4 + (threadIdx.x >> 6);
  if (g >= N_GRAPHS) return;
  int lane = threadIdx.x & 63;
  int li = lane & 15;
  int s0 = gptr[g], s1 = gptr[g + 1];
  float p[8];
#pragma unroll
  for (int j = 0; j < 8; j++) p[j] = 0.f;
  int f1 = s1 * 16;
  for (int f = s0 * 16 + lane; f < f1; f += 64) {
    uint4 v = ((const uint4*)h)[f];
    accum8(p, v);
  }
#pragma unroll
  for (int j = 0; j < 8; j++) {
    p[j] += __shfl_xor(p[j], 16, 64);
    p[j] += __shfl_xor(p[j], 32, 64);
  }
  float inv = (s1 > s0) ? 1.f / (float)(s1 - s0) : 0.f;
  if (lane < 16) {
    float4 o0 = make_float4(p[0] * inv, p[1] * inv, p[2] * inv, p[3] * inv);
    float4 o1 = make_float4(p[4] * inv, p[5] * inv, p[6] * inv, p[7] * inv);
    *(float4*)(pooledMean + g * DIM + li * 8) = o0;
    *(float4*)(pooledMean + g * DIM + li * 8 + 4) = o1;
  }
}

// ---------------- fused FC head, 16 graphs per block ----------------
#define GPB 16
__global__ __launch_bounds__(256) void k_fc2(const float* __restrict__ pooledMean,
                                             const float* __restrict__ fc_w, const float* __restrict__ fc_b,
                                             const float* __restrict__ reg_w, const float* __restrict__ reg_b,
                                             float* __restrict__ out) {
  __shared__ float sp[GPB][128];
  __shared__ float shfc[GPB][257];
  int g0 = blockIdx.x * GPB, t = threadIdx.x;
  for (int k = t; k < GPB * 128; k += 256) sp[k >> 7][k & 127] = pooledMean[g0 * 128 + k];
  __syncthreads();
  float a[GPB];
  float fb = fc_b[t];
#pragma unroll
  for (int g = 0; g < GPB; g++) a[g] = fb;
  for (int k = 0; k < 128; k++) {
    float w = fc_w[k * 256 + t];
#pragma unroll
    for (int g = 0; g < GPB; g++) a[g] += sp[g][k] * w;
  }
#pragma unroll
  for (int g = 0; g < GPB; g++) shfc[g][t] = a[g];
  __syncthreads();
  if (t < GPB * 8) {
    int g = t >> 3, o = t & 7;
    float r = reg_b[o];
    for (int j = 0; j < 256; j++) r += shfc[g][j] * reg_w[j * 8 + o];
    out[(g0 + g) * 8 + o] = r;
  }
}

extern "C" void kernel_launch(void* const* d_in, const int* in_sizes, int n_in,
                              void* d_out, int out_size, void* d_ws, size_t ws_size,
                              hipStream_t stream) {
  (void)in_sizes; (void)n_in; (void)out_size; (void)ws_size;
  const float* x = (const float*)d_in[0];
  const int* ei = (const int*)d_in[1];
  const int* src = ei;
  const int* dst = ei + N_EDGES;
  const int* batch = (const int*)d_in[2];
  const float* Wrel[4]  = {(const float*)d_in[3], (const float*)d_in[6], (const float*)d_in[9],  (const float*)d_in[12]};
  const float* Wroot[4] = {(const float*)d_in[4], (const float*)d_in[7], (const float*)d_in[10], (const float*)d_in[13]};
  const float* bias[4]  = {(const float*)d_in[5], (const float*)d_in[8], (const float*)d_in[11], (const float*)d_in[14]};
  const float* fc_w  = (const float*)d_in[15];
  const float* fc_b  = (const float*)d_in[16];
  const float* reg_w = (const float*)d_in[17];
  const float* reg_b = (const float*)d_in[18];
  float* out = (float*)d_out;

  char* ws = (char*)d_ws;
  size_t off = 0;
  auto alloc = [&](size_t b) -> char* {
    char* p = ws + off;
    off = (off + b + 255) & ~(size_t)255;
    return p;
  };
  int* rowptr = (int*)alloc((N_NODES + 1) * 4);
  int* cntmat = (int*)alloc((size_t)NMAT * 4);
  int* tmpB   = (int*)alloc((size_t)NMAT * 4);
  int* bsumB  = (int*)alloc(128 * 4);
  int* base   = (int*)alloc((size_t)NMAT * 4);
  int2* epk   = (int2*)alloc((size_t)N_EDGES * 8);
  int* colws  = (int*)alloc((size_t)N_EDGES * 4);
  int* gptr   = (int*)alloc((N_GRAPHS + 1) * 4);
  unsigned short* wbF = (unsigned short*)alloc((size_t)4 * 32768 * 2);
  unsigned short* h_a = (unsigned short*)alloc((size_t)N_NODES * DIM * 2);
  unsigned short* h_b = (unsigned short*)alloc((size_t)N_NODES * DIM * 2);
  unsigned char* q_a  = (unsigned char*)alloc((size_t)N_NODES * DIM);
  unsigned char* q_b  = (unsigned char*)alloc((size_t)N_NODES * DIM);
  float* sc_a = (float*)alloc((size_t)N_NODES * 4);
  float* sc_b = (float*)alloc((size_t)N_NODES * 4);
  float* pooled = (float*)alloc((size_t)N_GRAPHS * DIM * 4);

  // bucket CSR build
  k_bcount<<<NCH, 256, 0, stream>>>(dst, cntmat);
  k_scan1g<<<NMAT / 1024, 256, 0, stream>>>(cntmat, NMAT, tmpB, bsumB);
  k_scan2g<<<1, 128, 0, stream>>>(bsumB, NMAT / 1024);
  k_exc<<<(NMAT + 255) / 256, 256, 0, stream>>>(tmpB, bsumB, cntmat, NMAT, base);
  k_bscatter<<<NCH, 256, 0, stream>>>(src, dst, base, epk);
  k_bfinish<<<NBUK, 256, 0, stream>>>(epk, base, rowptr, colws);

  k_gptr<<<(N_NODES + 255) / 256, 256, 0, stream>>>(batch, gptr);
  k_cvtx<<<(N_NODES * DIM / 4 + 255) / 256, 256, 0, stream>>>(x, h_a);
  k_cvtq<<<N_NODES / 4, 256, 0, stream>>>(x, q_a, sc_a);
  k_cvtw<<<(4 * 32768 + 255) / 256, 256, 0, stream>>>(
      Wrel[0], Wroot[0], Wrel[1], Wroot[1], Wrel[2], Wroot[2], Wrel[3], Wroot[3], wbF);

  unsigned short* h_in = h_a; unsigned short* h_out = h_b;
  unsigned char* q_in = q_a;  unsigned char* q_out = q_b;
  float* s_in = sc_a;         float* s_out = sc_b;
  const int FB = N_NODES / 16;  // 6250 one-wave blocks
  for (int l = 0; l < 4; l++) {
    k_fused<<<FB, 64, 0, stream>>>(rowptr, colws, h_in, q_in, s_in,
                                   wbF + (size_t)l * 32768, bias[l], h_out, q_out, s_out);
    unsigned short* t2 = h_in; h_in = h_out; h_out = t2;
    unsigned char* t3 = q_in;  q_in = q_out;  q_out = t3;
    float* t4 = s_in;          s_in = s_out;  s_out = t4;
  }
  // final features in h_in

  k_pool<<<(N_GRAPHS + 3) / 4, 256, 0, stream>>>(h_in, gptr, pooled);
  k_fc2<<<N_GRAPHS / GPB, 256, 0, stream>>>(pooled, fc_w, fc_b, reg_w, reg_b, out);
}